// Round 7
// baseline (206.427 us; speedup 1.0000x reference)
//
#include <hip/hip_runtime.h>
#include <hip/hip_bf16.h>

// Conv2d B=32 IC=128 112x112 -> OC=256, K=3, s=2, p=1 (OH=OW=56).
// Round 7: FUSED implicit GEMM — no xt intermediate (saves 210MB HBM + a pass).
//   k2 wtrans2: w OIHW f32 -> per-K-step granule-major bf16 images
//               wt2[step=tap*4+icc][q][oc][8ic], 16KB contiguous per step.
//   k3 conv_fused: BM=256(all oc) x BN=64 pix x BK=32, 4 waves, grid 1568.
//     X staged from NCHW f32 in-kernel: 8 coalesced loads/thread/step,
//     cvt_pk bf16, single 16B ds_write into granule-major LDS [q][pix][8].
//     W via 4 linear global_load_lds(16B) from wt2. 2-phase dbuf, loads
//     issued before MFMAs / written after (T14). XCD swizzle chunk 196.

#define B_    32
#define IC_   128
#define H_    112
#define W_    112
#define HW_   (H_ * W_)
#define OC_   256
#define OH_   56
#define OW_   56
#define NPIX  (B_ * OH_ * OW_)            // 100352
#define NTILE (NPIX / 64)                 // 1568 blocks
#define WT2_BYTES ((size_t)36 * 16384)    // 589,824

typedef __attribute__((ext_vector_type(8))) short bf16x8;
typedef __attribute__((ext_vector_type(4))) float f32x4;

static __device__ __forceinline__ unsigned f2bf_u(float f) {
  union { float f; unsigned u; } v; v.f = f;
  return (v.u + 0x7FFF + ((v.u >> 16) & 1)) >> 16;   // RNE; inputs finite
}

static __device__ __forceinline__ unsigned pk_bf16(float a, float b) {
  union { __hip_bfloat162 h; unsigned u; } c;
  c.h = __float22bfloat162_rn(float2{a, b});          // v_cvt_pk_bf16_f32
  return c.u;
}

// ---------------- k2: w -> wt2[step][q][oc][8] bf16 ----------------
__global__ __launch_bounds__(256) void wtrans2_kernel(
    const float* __restrict__ w, unsigned short* __restrict__ wt2) {
  const int t  = blockIdx.x * 256 + threadIdx.x;   // oc*128 + ic
  const int oc = t >> 7;
  const int ic = t & 127;
  const int icc = ic >> 5, q = (ic >> 3) & 3, e = ic & 7;
  const float* ws = w + (size_t)t * 9;             // w[oc][ic][*]
#pragma unroll
  for (int tap = 0; tap < 9; ++tap) {
    const int step = tap * 4 + icc;
    wt2[((size_t)(step * 4 + q) * 256 + oc) * 8 + e] =
        (unsigned short)f2bf_u(ws[tap]);
  }
}

// ---------------- k3: fused conv MFMA ----------------
__global__ __launch_bounds__(256) void conv_fused_kernel(
    const float* __restrict__ x, const unsigned short* __restrict__ wt2,
    const float* __restrict__ bias, float* __restrict__ out) {
  __shared__ unsigned short Wl[2][8192];  // [buf][q][256 oc][8ic] 16KB each
  __shared__ unsigned short Xl[2][2048];  // [buf][q][64 pix][8ic]  4KB each

  const int tid = threadIdx.x, wav = tid >> 6, lane = tid & 63;

  // XCD-chunk swizzle: 1568 = 8*196, bijective.
  const int bid = blockIdx.x;
  const int pt  = (bid & 7) * (NTILE / 8) + (bid >> 3);
  const int p0  = pt * 64;
  const int b   = p0 / 3136;               // 64 | 3136: block never crosses b
  const int q0  = p0 - b * 3136;

  // Per-thread pixel (lane = pixel within tile; fixed for whole K-loop).
  const int pixq = q0 + lane;
  const int oh = pixq / 56, ow = pixq - oh * 56;
  const int ih0 = 2 * oh - 1, iw0 = 2 * ow - 1;    // only -1 can be OOB
  const int boff = ih0 * W_ + iw0;
  const float* xpl = x + (size_t)b * IC_ * HW_;

  unsigned mtap = 0;                        // per-tap validity bitmask
#pragma unroll
  for (int kh = 0; kh < 3; ++kh)
#pragma unroll
    for (int kw = 0; kw < 3; ++kw)
      if (ih0 + kh >= 0 && iw0 + kw >= 0) mtap |= 1u << (kh * 3 + kw);

  const int l15 = lane & 15, lg = lane >> 4;

  auto loadX = [&](int s, float* v) {       // issue 8 coalesced f32 loads
    const int tap = s >> 2, icc = s & 3;
    const int kh = tap / 3, kw = tap - kh * 3;
    const bool m = (mtap >> tap) & 1;
    const int o = boff + kh * W_ + kw + (icc * 32 + wav * 8) * HW_;
#pragma unroll
    for (int k = 0; k < 8; ++k)
      v[k] = m ? xpl[o + k * HW_] : 0.f;
  };
  auto writeX = [&](const float* v, int buf) {   // pack + 16B LDS write
    uint4 p;
    p.x = pk_bf16(v[0], v[1]);
    p.y = pk_bf16(v[2], v[3]);
    p.z = pk_bf16(v[4], v[5]);
    p.w = pk_bf16(v[6], v[7]);
    *reinterpret_cast<uint4*>(
        reinterpret_cast<char*>(&Xl[buf][0]) + wav * 1024 + lane * 16) = p;
  };
  auto stageW = [&](int s, int buf) {       // 4 linear global_load_lds 16B
    const char* src = reinterpret_cast<const char*>(wt2)
                    + (size_t)s * 16384 + wav * 1024 + lane * 16;
    char* dst = reinterpret_cast<char*>(&Wl[buf][0]) + wav * 1024;
#pragma unroll
    for (int shot = 0; shot < 4; ++shot)
      __builtin_amdgcn_global_load_lds(
          (const __attribute__((address_space(1))) void*)(src + shot * 4096),
          (__attribute__((address_space(3))) void*)(dst + shot * 4096),
          16, 0, 0);
  };

  f32x4 acc[4][4] = {};

  auto compute = [&](int buf) {
    bf16x8 af[4], bx[4];
    const unsigned short* wb  = &Wl[buf][0] + lg * 2048;  // q stride 4KB
    const unsigned short* xb2 = &Xl[buf][0] + lg * 512;   // q stride 1KB
#pragma unroll
    for (int mi = 0; mi < 4; ++mi)
      af[mi] = *reinterpret_cast<const bf16x8*>(
          wb + (wav * 64 + mi * 16 + l15) * 8);
#pragma unroll
    for (int ni = 0; ni < 4; ++ni)
      bx[ni] = *reinterpret_cast<const bf16x8*>(xb2 + (ni * 16 + l15) * 8);
#pragma unroll
    for (int mi = 0; mi < 4; ++mi)
#pragma unroll
      for (int ni = 0; ni < 4; ++ni)
        acc[mi][ni] = __builtin_amdgcn_mfma_f32_16x16x32_bf16(
            af[mi], bx[ni], acc[mi][ni], 0, 0, 0);
  };

  // Prologue: step 0 -> buf0.
  {
    float v[8];
    loadX(0, v); stageW(0, 0); writeX(v, 0);
  }
  __syncthreads();

  // 36 K-steps (9 taps x 4 ic-chunks), step s lives in buf (s&1).
  for (int s = 0; s < 36; s += 2) {
    float v[8];
    loadX(s + 1, v);                 // issue loads for next step
    stageW(s + 1, 1);
    compute(0);                      // MFMAs on current buffer
    writeX(v, 1);                    // waits only its own loads (vmcnt)
    __syncthreads();
    const bool more = (s + 2 < 36);
    if (more) { loadX(s + 2, v); stageW(s + 2, 0); }
    compute(1);
    if (more) { writeX(v, 0); }
    __syncthreads();
  }

  // Epilogue: lanes sweep pixels -> coalesced 64B quarter-wave stores.
#pragma unroll
  for (int mi = 0; mi < 4; ++mi) {
#pragma unroll
    for (int j = 0; j < 4; ++j) {
      const int oc = wav * 64 + mi * 16 + lg * 4 + j;
      const float bv = bias[oc];
#pragma unroll
      for (int ni = 0; ni < 4; ++ni) {
        const int qp = q0 + ni * 16 + l15;
        out[((size_t)b * OC_ + oc) * 3136 + qp] = acc[mi][ni][j] + bv;
      }
    }
  }
}

// ---------------- fallback: fp32 direct conv ----------------
__global__ __launch_bounds__(256) void conv2d_f32_kernel(
    const float* __restrict__ x, const float* __restrict__ w,
    const float* __restrict__ bias, float* __restrict__ out) {
  __shared__ float wlds[IC_ * 9][8];
  const int b   = blockIdx.z;
  const int oc0 = blockIdx.y * 8;
  const float* wsrc = w + (size_t)oc0 * (IC_ * 9);
  for (int i = threadIdx.x; i < IC_ * 9 * 8; i += 256) {
    const int j = i / (IC_ * 9);
    const int t = i - j * (IC_ * 9);
    wlds[t][j] = wsrc[(size_t)j * (IC_ * 9) + t];
  }
  __syncthreads();
  const int p  = blockIdx.x * 256 + threadIdx.x;
  const int ow = p % OW_;
  const int oh = p / OW_;
  const bool pv = (oh < OH_);
  const int ih0 = 2 * oh - 1;
  const int iw0 = 2 * ow - 1;
  const float* xb = x + (size_t)b * IC_ * HW_ + (ptrdiff_t)ih0 * W_ + iw0;
  float acc[8];
#pragma unroll
  for (int j = 0; j < 8; ++j) acc[j] = 0.f;
  for (int ic = 0; ic < IC_; ++ic) {
    const float* xc = xb + (size_t)ic * HW_;
#pragma unroll
    for (int kh = 0; kh < 3; ++kh) {
      const bool hv = pv && ((ih0 + kh) >= 0);
#pragma unroll
      for (int kw = 0; kw < 3; ++kw) {
        const bool v = hv && ((iw0 + kw) >= 0);
        const float xv = v ? xc[kh * W_ + kw] : 0.f;
        const int t = ic * 9 + kh * 3 + kw;
        const float4 w0 = *reinterpret_cast<const float4*>(&wlds[t][0]);
        const float4 w1 = *reinterpret_cast<const float4*>(&wlds[t][4]);
        acc[0] = fmaf(xv, w0.x, acc[0]); acc[1] = fmaf(xv, w0.y, acc[1]);
        acc[2] = fmaf(xv, w0.z, acc[2]); acc[3] = fmaf(xv, w0.w, acc[3]);
        acc[4] = fmaf(xv, w1.x, acc[4]); acc[5] = fmaf(xv, w1.y, acc[5]);
        acc[6] = fmaf(xv, w1.z, acc[6]); acc[7] = fmaf(xv, w1.w, acc[7]);
      }
    }
  }
  if (pv) {
#pragma unroll
    for (int j = 0; j < 8; ++j)
      out[(((size_t)(b * OC_ + oc0 + j)) * OH_ + oh) * OW_ + ow] =
          acc[j] + bias[oc0 + j];
  }
}

extern "C" void kernel_launch(void* const* d_in, const int* in_sizes, int n_in,
                              void* d_out, int out_size, void* d_ws, size_t ws_size,
                              hipStream_t stream) {
  const float* x    = (const float*)d_in[0];
  const float* w    = (const float*)d_in[1];
  const float* bias = (const float*)d_in[2];
  float* out        = (float*)d_out;

  if (ws_size >= WT2_BYTES) {
    unsigned short* wt2 = (unsigned short*)d_ws;
    wtrans2_kernel<<<128, 256, 0, stream>>>(w, wt2);
    conv_fused_kernel<<<NTILE, 256, 0, stream>>>(x, wt2, bias, out);
  } else {
    conv2d_f32_kernel<<<dim3(13, OC_ / 8, B_), 256, 0, stream>>>(x, w, bias, out);
  }
}